// Round 1
// baseline (368.139 us; speedup 1.0000x reference)
//
#include <hip/hip_runtime.h>
#include <math.h>

#define D 100
#define NEG_SLOPE 0.2f

__device__ __forceinline__ float wave_reduce_max(float x) {
    #pragma unroll
    for (int off = 32; off > 0; off >>= 1)
        x = fmaxf(x, __shfl_xor(x, off, 64));
    return x;
}

__device__ __forceinline__ float wave_reduce_sum(float x) {
    #pragma unroll
    for (int off = 32; off > 0; off >>= 1)
        x += __shfl_xor(x, off, 64);
    return x;
}

__device__ __forceinline__ int lower_bound(const int* __restrict__ a, int nelem, int key) {
    int lo = 0, hi = nelem;
    while (lo < hi) {
        int mid = (lo + hi) >> 1;
        if (a[mid] < key) lo = mid + 1; else hi = mid;
    }
    return lo;
}

// One wave (64 lanes) per node v. Pairs for v are the contiguous run
// seg[start..end) (seg sorted by construction: np.unique sorts rows).
__launch_bounds__(256, 4)
__global__ void gat_agg_kernel(const float* __restrict__ hidden,
                               const float* __restrict__ W,
                               const int* __restrict__ seg,
                               const int* __restrict__ nbr,
                               float* __restrict__ out,
                               int n, int P)
{
    __shared__ __align__(16) float s_hw[4][104];   // per-wave hw vector, 16B aligned rows

    const int lane = threadIdx.x & 63;
    const int wid  = threadIdx.x >> 6;
    const int v    = blockIdx.x * 4 + wid;
    if (v >= n) return;   // whole-wave uniform exit; no block barriers used anywhere

    // hw[d] = hidden[v][d] * W[d]  (staged once, broadcast-read in the dot loop)
    s_hw[wid][lane] = hidden[(long)v * D + lane] * W[lane];
    if (lane < D - 64)
        s_hw[wid][64 + lane] = hidden[(long)v * D + 64 + lane] * W[64 + lane];
    __threadfence_block();   // order LDS write -> read within the wave

    const float4* hw4 = (const float4*)&s_hw[wid][0];

    const int start = lower_bound(seg, P, v);
    const int end   = lower_bound(seg, P, v + 1);

    float m = -INFINITY, z = 0.f;
    float accx = 0.f, accy = 0.f;

    for (int c = start; c < end; c += 64) {
        const int cnt   = min(64, end - c);
        const bool valid = lane < cnt;

        // ---- Phase A: lane-per-pair gather-dot -> score ----
        int   nbv = 0;
        float s   = -INFINITY;
        if (valid) {
            nbv = nbr[c + lane];
            const float4* row4 = (const float4*)(hidden + (long)nbv * D);
            float acc = 0.f;
            #pragma unroll
            for (int k = 0; k < D / 4; k++) {
                float4 a = hw4[k];     // LDS broadcast (all lanes same addr)
                float4 b = row4[k];    // per-lane contiguous 16B gather
                acc += a.x * b.x + a.y * b.y + a.z * b.z + a.w * b.w;
            }
            s = (acc >= 0.f) ? acc : NEG_SLOPE * acc;   // leaky_relu
        }

        // ---- online softmax update ----
        const float m_new = fmaxf(m, wave_reduce_max(s));
        const float scale = expf(m - m_new);            // first chunk: exp(-inf)=0
        const float e     = valid ? expf(s - m_new) : 0.f;
        z = z * scale + wave_reduce_sum(e);
        accx *= scale; accy *= scale;

        // ---- Phase B: lane-per-dim accumulate (float2: 50 lanes cover D=100) ----
        if (lane < D / 2) {
            for (int j = 0; j < cnt; j++) {
                const float ej = __shfl(e,   j, 64);    // broadcast from lane j
                const int   nb = __shfl(nbv, j, 64);
                const float2 r = ((const float2*)(hidden + (long)nb * D))[lane];
                accx += ej * r.x;
                accy += ej * r.y;
            }
        }
        m = m_new;
    }

    if (lane < D / 2) {
        const float inv = 1.f / z;
        out[(long)v * D + 2 * lane]     = accx * inv;
        out[(long)v * D + 2 * lane + 1] = accy * inv;
    }
}

extern "C" void kernel_launch(void* const* d_in, const int* in_sizes, int n_in,
                              void* d_out, int out_size, void* d_ws, size_t ws_size,
                              hipStream_t stream) {
    const float* hidden = (const float*)d_in[0];
    const float* W      = (const float*)d_in[1];
    const int*   seg    = (const int*)d_in[2];
    const int*   nbr    = (const int*)d_in[3];
    float*       out    = (float*)d_out;

    const int Ddim = in_sizes[1];           // 100
    const int n    = in_sizes[0] / Ddim;    // 50000
    const int P    = in_sizes[2];           // ~1.3M pairs

    dim3 block(256);
    dim3 grid((n + 3) / 4);                 // 4 nodes (waves) per block
    hipLaunchKernelGGL(gat_agg_kernel, grid, block, 0, stream,
                       hidden, W, seg, nbr, out, n, P);
}

// Round 2
// 233.527 us; speedup vs baseline: 1.5764x; 1.5764x over previous
//
#include <hip/hip_runtime.h>
#include <math.h>

#define D 100
#define NEG_SLOPE 0.2f

__device__ __forceinline__ float wave_reduce_max(float x) {
    #pragma unroll
    for (int off = 32; off > 0; off >>= 1)
        x = fmaxf(x, __shfl_xor(x, off, 64));
    return x;
}

__device__ __forceinline__ float wave_reduce_sum(float x) {
    #pragma unroll
    for (int off = 32; off > 0; off >>= 1)
        x += __shfl_xor(x, off, 64);
    return x;
}

// Pair-parallel boundary scatter: row_ptr[v] = first pair index with seg >= v.
// seg is sorted (np.unique); every node present (ring edges), but the loop
// form also handles hypothetical gaps (empty segments -> start == end).
__global__ void build_row_ptr(const int* __restrict__ seg,
                              int* __restrict__ row_ptr,
                              int n, int P)
{
    int p = blockIdx.x * blockDim.x + threadIdx.x;
    if (p >= P) return;
    int s0 = seg[p];
    if (p == 0)
        for (int v = 0; v <= s0; v++) row_ptr[v] = 0;
    int s1 = (p + 1 < P) ? seg[p + 1] : n;
    for (int v = s0 + 1; v <= s1; v++) row_ptr[v] = p + 1;
}

// One wave per node. Phase A: 2 lanes per pair (chunk of 32 pairs); lane j
// dots float4s [0..12], lane j+32 dots [13..24] of the same neighbor row ->
// 13 load issues instead of 25 and ~81% lane utilization at mean degree 26.
__launch_bounds__(256, 4)
__global__ void gat_agg_kernel(const float* __restrict__ hidden,
                               const float* __restrict__ W,
                               const int* __restrict__ nbr,
                               const int* __restrict__ row_ptr,
                               float* __restrict__ out,
                               int n)
{
    __shared__ __align__(16) float s_hw[4][104];

    const int lane = threadIdx.x & 63;
    const int wid  = threadIdx.x >> 6;
    const int v    = blockIdx.x * 4 + wid;
    if (v >= n) return;          // wave-uniform exit; no block barriers used

    // hw[d] = hidden[v][d] * W[d], staged once in LDS (broadcast source)
    s_hw[wid][lane] = hidden[(long)v * D + lane] * W[lane];
    if (lane < D - 64)
        s_hw[wid][64 + lane] = hidden[(long)v * D + 64 + lane] * W[64 + lane];
    __threadfence_block();

    const float4* hw4 = (const float4*)&s_hw[wid][0];

    const int start = row_ptr[v];
    const int end   = row_ptr[v + 1];

    if (end <= start) {          // empty segment: reference yields zeros
        if (lane < D / 2)
            ((float2*)(out + (long)v * D))[lane] = make_float2(0.f, 0.f);
        return;
    }

    const int half = lane >> 5;          // 0: float4s 0..12, 1: 13..24
    const int jl   = lane & 31;          // pair slot within the 32-chunk

    float m = -INFINITY, z = 0.f;
    float accx = 0.f, accy = 0.f;

    for (int c = start; c < end; c += 32) {
        const int  cnt = min(32, end - c);
        const bool pv  = jl < cnt;

        // ---- Phase A: split gather-dot -> score ----
        const int nbv = pv ? nbr[c + jl] : 0;
        const float4* row4 = (const float4*)(hidden + (long)nbv * D) + half * 13;
        const float4* hwh  = hw4 + half * 13;
        float part = 0.f;
        if (pv) {
            #pragma unroll
            for (int k = 0; k < 12; k++) {
                float4 a = hwh[k];       // LDS: 2 addrs/wave -> conflict-free
                float4 b = row4[k];      // 16B per-lane gather
                part += a.x * b.x + a.y * b.y + a.z * b.z + a.w * b.w;
            }
            if (half == 0) {             // odd float4 (12) handled by half 0
                float4 a = hw4[12];
                float4 b = row4[12];
                part += a.x * b.x + a.y * b.y + a.z * b.z + a.w * b.w;
            }
        }
        part += __shfl_xor(part, 32, 64);                 // combine halves
        const float s = pv ? (part >= 0.f ? part : NEG_SLOPE * part)
                           : -INFINITY;

        // ---- online softmax (e counted once, on half 0) ----
        const float m_new = fmaxf(m, wave_reduce_max(s));
        const float scale = __expf(m - m_new);            // first chunk: 0
        const float e     = (pv && half == 0) ? __expf(s - m_new) : 0.f;
        z = z * scale + wave_reduce_sum(e);
        accx *= scale; accy *= scale;

        // ---- Phase B: lane-per-dim accumulate, unrolled x4 ----
        // tail j >= cnt broadcasts e=0, nbv=0 -> harmless read of row 0
        const int cnt4 = (cnt + 3) & ~3;
        if (lane < D / 2) {
            #pragma unroll 4
            for (int j = 0; j < cnt4; j++) {
                const float ej = __shfl(e,   j, 64);
                const int   nb = __shfl(nbv, j, 64);
                const float2 r = ((const float2*)(hidden + (long)nb * D))[lane];
                accx += ej * r.x;
                accy += ej * r.y;
            }
        }
        m = m_new;
    }

    if (lane < D / 2) {
        const float inv = 1.f / z;
        ((float2*)(out + (long)v * D))[lane] = make_float2(accx * inv, accy * inv);
    }
}

extern "C" void kernel_launch(void* const* d_in, const int* in_sizes, int n_in,
                              void* d_out, int out_size, void* d_ws, size_t ws_size,
                              hipStream_t stream) {
    const float* hidden = (const float*)d_in[0];
    const float* W      = (const float*)d_in[1];
    const int*   seg    = (const int*)d_in[2];
    const int*   nbr    = (const int*)d_in[3];
    float*       out    = (float*)d_out;

    const int Ddim = in_sizes[1];           // 100
    const int n    = in_sizes[0] / Ddim;    // 50000
    const int P    = in_sizes[2];           // ~1.3M pairs

    int* row_ptr = (int*)d_ws;              // (n+1) ints, ws is plenty

    hipLaunchKernelGGL(build_row_ptr, dim3((P + 255) / 256), dim3(256), 0, stream,
                       seg, row_ptr, n, P);
    hipLaunchKernelGGL(gat_agg_kernel, dim3((n + 3) / 4), dim3(256), 0, stream,
                       hidden, W, nbr, row_ptr, out, n);
}

// Round 3
// 197.717 us; speedup vs baseline: 1.8619x; 1.1811x over previous
//
#include <hip/hip_runtime.h>
#include <math.h>

#define D 100
#define NEG_SLOPE 0.2f
#define CHUNK 32

__device__ __forceinline__ float wave_reduce_max(float x) {
    #pragma unroll
    for (int off = 32; off > 0; off >>= 1)
        x = fmaxf(x, __shfl_xor(x, off, 64));
    return x;
}

__device__ __forceinline__ float wave_reduce_sum(float x) {
    #pragma unroll
    for (int off = 32; off > 0; off >>= 1)
        x += __shfl_xor(x, off, 64);
    return x;
}

// Pair-parallel boundary scatter: row_ptr[v] = first pair index with seg >= v.
__global__ void build_row_ptr(const int* __restrict__ seg,
                              int* __restrict__ row_ptr,
                              int n, int P)
{
    int p = blockIdx.x * blockDim.x + threadIdx.x;
    if (p >= P) return;
    int s0 = seg[p];
    if (p == 0)
        for (int v = 0; v <= s0; v++) row_ptr[v] = 0;
    int s1 = (p + 1 < P) ? seg[p + 1] : n;
    for (int v = s0 + 1; v <= s1; v++) row_ptr[v] = p + 1;
}

// One wave per node. Phase A: 2 lanes per pair gather-dot AND stage the row
// into LDS. Phase B: lane-per-dim weighted accumulate reading LDS only.
// Each neighbor row crosses the global path exactly ONCE per pair.
__launch_bounds__(256, 3)   // LDS (51.2K/block) caps at 3 blocks/CU anyway
__global__ void gat_agg_kernel(const float* __restrict__ hidden,
                               const float* __restrict__ W,
                               const int* __restrict__ nbr,
                               const int* __restrict__ row_ptr,
                               float* __restrict__ out,
                               int n)
{
    __shared__ __align__(16) float s_hw[4][104];
    __shared__ __align__(16) float s_rows[4][CHUNK][D];   // 51.2 KB, stride 400 B

    const int lane = threadIdx.x & 63;
    const int wid  = threadIdx.x >> 6;
    const int v    = blockIdx.x * 4 + wid;
    if (v >= n) return;          // wave-uniform exit; no block barriers used

    // hw[d] = hidden[v][d] * W[d], staged once in LDS (broadcast source)
    s_hw[wid][lane] = hidden[(long)v * D + lane] * W[lane];
    if (lane < D - 64)
        s_hw[wid][64 + lane] = hidden[(long)v * D + 64 + lane] * W[64 + lane];
    __threadfence_block();

    const float4* hw4 = (const float4*)&s_hw[wid][0];

    const int start = row_ptr[v];
    const int end   = row_ptr[v + 1];

    if (end <= start) {          // empty segment: zeros (matches reference)
        if (lane < D / 2)
            ((float2*)(out + (long)v * D))[lane] = make_float2(0.f, 0.f);
        return;
    }

    const int half = lane >> 5;          // 0: floats 0..51, 1: floats 52..99
    const int jl   = lane & 31;          // pair slot within the 32-chunk

    float m = -INFINITY, z = 0.f;
    float accx = 0.f, accy = 0.f;

    for (int c = start; c < end; c += CHUNK) {
        const int  cnt = min(CHUNK, end - c);
        const bool pv  = jl < cnt;

        // ---- Phase A: gather-dot + LDS staging ----
        const int nbv = pv ? nbr[c + jl] : 0;
        const float4* row4 = (const float4*)(hidden + (long)nbv * D) + half * 13;
        const float4* hwh  = hw4 + half * 13;
        float4* dst4 = (float4*)&s_rows[wid][jl][half * 52];

        float part = 0.f;
        if (pv) {
            #pragma unroll
            for (int k = 0; k < 12; k++) {
                float4 b = row4[k];      // single global read of the row
                float4 a = hwh[k];
                part += a.x * b.x + a.y * b.y + a.z * b.z + a.w * b.w;
                dst4[k] = b;             // stage for phase B
            }
            if (half == 0) {             // odd float4 handled by half 0
                float4 b = row4[12];
                float4 a = hw4[12];
                part += a.x * b.x + a.y * b.y + a.z * b.z + a.w * b.w;
                dst4[12] = b;
            }
        } else {
            // zero-fill so the unrolled phase-B tail reads 0*0, never poison
            const float4 zz = make_float4(0.f, 0.f, 0.f, 0.f);
            #pragma unroll
            for (int k = 0; k < 12; k++) dst4[k] = zz;
            if (half == 0) dst4[12] = zz;
        }
        part += __shfl_xor(part, 32, 64);                 // combine halves
        const float s = pv ? (part >= 0.f ? part : NEG_SLOPE * part)
                           : -INFINITY;

        // ---- online softmax (e counted once, on half 0) ----
        const float m_new = fmaxf(m, wave_reduce_max(s));
        const float scale = __expf(m - m_new);            // first chunk: 0
        const float e     = (pv && half == 0) ? __expf(s - m_new) : 0.f;
        z = z * scale + wave_reduce_sum(e);
        accx *= scale; accy *= scale;

        __threadfence_block();   // LDS stores -> reads ordering within the wave

        // ---- Phase B: lane-per-dim accumulate from LDS ----
        const int cnt4 = (cnt + 3) & ~3;
        if (lane < D / 2) {
            #pragma unroll 4
            for (int j = 0; j < cnt4; j++) {
                const float ej = __shfl(e, j, 64);   // e lives on lane j (half 0)
                const float2 r = ((const float2*)&s_rows[wid][j][0])[lane];
                accx += ej * r.x;
                accy += ej * r.y;
            }
        }
        __threadfence_block();   // phase-B reads done before next chunk's stores
        m = m_new;
    }

    if (lane < D / 2) {
        const float inv = 1.f / z;
        ((float2*)(out + (long)v * D))[lane] = make_float2(accx * inv, accy * inv);
    }
}

extern "C" void kernel_launch(void* const* d_in, const int* in_sizes, int n_in,
                              void* d_out, int out_size, void* d_ws, size_t ws_size,
                              hipStream_t stream) {
    const float* hidden = (const float*)d_in[0];
    const float* W      = (const float*)d_in[1];
    const int*   seg    = (const int*)d_in[2];
    const int*   nbr    = (const int*)d_in[3];
    float*       out    = (float*)d_out;

    const int Ddim = in_sizes[1];           // 100
    const int n    = in_sizes[0] / Ddim;    // 50000
    const int P    = in_sizes[2];           // ~1.3M pairs

    int* row_ptr = (int*)d_ws;              // (n+1) ints

    hipLaunchKernelGGL(build_row_ptr, dim3((P + 255) / 256), dim3(256), 0, stream,
                       seg, row_ptr, n, P);
    hipLaunchKernelGGL(gat_agg_kernel, dim3((n + 3) / 4), dim3(256), 0, stream,
                       hidden, W, nbr, row_ptr, out, n);
}

// Round 4
// 182.611 us; speedup vs baseline: 2.0160x; 1.0827x over previous
//
#include <hip/hip_runtime.h>
#include <math.h>

#define D 100
#define NEG_SLOPE 0.2f
#define CHUNK 32
#define ROWU 50          // uints per staged bf16 row (100 dims * 2B / 4B)

__device__ __forceinline__ float wave_reduce_max(float x) {
    #pragma unroll
    for (int off = 32; off > 0; off >>= 1)
        x = fmaxf(x, __shfl_xor(x, off, 64));
    return x;
}

__device__ __forceinline__ float wave_reduce_sum(float x) {
    #pragma unroll
    for (int off = 32; off > 0; off >>= 1)
        x += __shfl_xor(x, off, 64);
    return x;
}

// pack two fp32 -> (bf16,bf16) in one uint, round-to-nearest-even
__device__ __forceinline__ unsigned int pack_bf16x2(float x, float y) {
    unsigned int ux = __float_as_uint(x), uy = __float_as_uint(y);
    ux += 0x7FFFu + ((ux >> 16) & 1u);
    uy += 0x7FFFu + ((uy >> 16) & 1u);
    return (ux >> 16) | (uy & 0xFFFF0000u);
}

// Pair-parallel boundary scatter: row_ptr[v] = first pair index with seg >= v.
__global__ void build_row_ptr(const int* __restrict__ seg,
                              int* __restrict__ row_ptr,
                              int n, int P)
{
    int p = blockIdx.x * blockDim.x + threadIdx.x;
    if (p >= P) return;
    int s0 = seg[p];
    if (p == 0)
        for (int v = 0; v <= s0; v++) row_ptr[v] = 0;
    int s1 = (p + 1 < P) ? seg[p + 1] : n;
    for (int v = s0 + 1; v <= s1; v++) row_ptr[v] = p + 1;
}

// One wave per node. Phase A: 2 lanes/pair gather-dot (exact fp32) + stage the
// row into LDS as packed bf16 (halves LDS vs fp32 -> 5 blocks/CU instead of 3).
// Phase B: lane-per-dim accumulate reading LDS only (1 shuffle per row).
__launch_bounds__(256, 5)
__global__ void gat_agg_kernel(const float* __restrict__ hidden,
                               const float* __restrict__ W,
                               const int* __restrict__ nbr,
                               const int* __restrict__ row_ptr,
                               float* __restrict__ out,
                               int n)
{
    __shared__ __align__(16) float        s_hw[4][104];           // 1.66 KB
    __shared__ __align__(16) unsigned int s_rows[4][CHUNK][ROWU]; // 25.6 KB

    const int lane = threadIdx.x & 63;
    const int wid  = threadIdx.x >> 6;
    const int v    = blockIdx.x * 4 + wid;
    if (v >= n) return;          // wave-uniform exit; no block barriers used

    // hw[d] = hidden[v][d] * W[d], staged once in LDS (broadcast source)
    s_hw[wid][lane] = hidden[(long)v * D + lane] * W[lane];
    if (lane < D - 64)
        s_hw[wid][64 + lane] = hidden[(long)v * D + 64 + lane] * W[64 + lane];
    __threadfence_block();

    const float4* hw4 = (const float4*)&s_hw[wid][0];

    const int start = row_ptr[v];
    const int end   = row_ptr[v + 1];

    if (end <= start) {          // empty segment: zeros (matches reference)
        if (lane < D / 2)
            ((float2*)(out + (long)v * D))[lane] = make_float2(0.f, 0.f);
        return;
    }

    const int half = lane >> 5;          // 0: float4s 0..12, 1: 13..24
    const int jl   = lane & 31;          // pair slot within the 32-chunk

    float m = -INFINITY, z = 0.f;
    float accx = 0.f, accy = 0.f;

    for (int c = start; c < end; c += CHUNK) {
        const int  cnt = min(CHUNK, end - c);
        const bool pv  = jl < cnt;

        // ---- Phase A: gather-dot (fp32) + bf16 LDS staging ----
        const int nbv = pv ? nbr[c + jl] : 0;
        const float4* row4 = (const float4*)(hidden + (long)nbv * D) + half * 13;
        const float4* hwh  = hw4 + half * 13;
        // half 0 stages uints [0..25] (dims 0..51), half 1 uints [26..49]
        uint2* dst = (uint2*)&s_rows[wid][jl][half * 26];

        float part = 0.f;
        if (pv) {
            #pragma unroll
            for (int k = 0; k < 12; k++) {
                float4 b = row4[k];      // single global read of the row
                float4 a = hwh[k];
                part += a.x * b.x + a.y * b.y + a.z * b.z + a.w * b.w;
                dst[k] = make_uint2(pack_bf16x2(b.x, b.y), pack_bf16x2(b.z, b.w));
            }
            if (half == 0) {             // odd float4 (k=12) handled by half 0
                float4 b = row4[12];
                float4 a = hw4[12];
                part += a.x * b.x + a.y * b.y + a.z * b.z + a.w * b.w;
                dst[12] = make_uint2(pack_bf16x2(b.x, b.y), pack_bf16x2(b.z, b.w));
            }
        } else {
            // zero-fill so the unrolled phase-B tail reads 0*0, never poison
            #pragma unroll
            for (int k = 0; k < 12; k++) dst[k] = make_uint2(0u, 0u);
            if (half == 0) dst[12] = make_uint2(0u, 0u);
        }
        part += __shfl_xor(part, 32, 64);                 // combine halves
        const float s = pv ? (part >= 0.f ? part : NEG_SLOPE * part)
                           : -INFINITY;

        // ---- online softmax (e counted once, on half 0) ----
        const float m_new = fmaxf(m, wave_reduce_max(s));
        const float scale = __expf(m - m_new);            // first chunk: 0
        const float e     = (pv && half == 0) ? __expf(s - m_new) : 0.f;
        z = z * scale + wave_reduce_sum(e);
        accx *= scale; accy *= scale;

        __threadfence_block();   // LDS stores -> reads ordering

        // ---- Phase B: lane-per-dim accumulate from bf16 LDS ----
        const int cnt4 = (cnt + 3) & ~3;
        if (lane < D / 2) {
            #pragma unroll 4
            for (int j = 0; j < cnt4; j++) {
                const float ej = __shfl(e, j, 64);   // e lives on lane j (half 0)
                const unsigned int u = s_rows[wid][j][lane];
                const float rx = __uint_as_float(u << 16);
                const float ry = __uint_as_float(u & 0xFFFF0000u);
                accx += ej * rx;
                accy += ej * ry;
            }
        }
        __threadfence_block();   // phase-B reads done before next chunk's stores
        m = m_new;
    }

    if (lane < D / 2) {
        const float inv = 1.f / z;
        ((float2*)(out + (long)v * D))[lane] = make_float2(accx * inv, accy * inv);
    }
}

extern "C" void kernel_launch(void* const* d_in, const int* in_sizes, int n_in,
                              void* d_out, int out_size, void* d_ws, size_t ws_size,
                              hipStream_t stream) {
    const float* hidden = (const float*)d_in[0];
    const float* W      = (const float*)d_in[1];
    const int*   seg    = (const int*)d_in[2];
    const int*   nbr    = (const int*)d_in[3];
    float*       out    = (float*)d_out;

    const int Ddim = in_sizes[1];           // 100
    const int n    = in_sizes[0] / Ddim;    // 50000
    const int P    = in_sizes[2];           // ~1.3M pairs

    int* row_ptr = (int*)d_ws;              // (n+1) ints

    hipLaunchKernelGGL(build_row_ptr, dim3((P + 255) / 256), dim3(256), 0, stream,
                       seg, row_ptr, n, P);
    hipLaunchKernelGGL(gat_agg_kernel, dim3((n + 3) / 4), dim3(256), 0, stream,
                       hidden, W, nbr, row_ptr, out, n);
}